// Round 1
// baseline (294.598 us; speedup 1.0000x reference)
//
#include <hip/hip_runtime.h>
#include <math.h>

#define NNODES 8192
#define DIM 256
#define ALPHA 3.0f
#define SLOPE 0.2f
#define LOG2E 1.4426950408889634f

// ---------------------------------------------------------------------------
// Kernel A: per-node scores s1[n] = tanh(a*emb1[idx[n]]) . w[:256]
//                           s2[n] = tanh(a*emb2[idx[n]]) . w[256:]
// One wave (64 lanes) per node; each lane handles 4 contiguous floats (float4).
// ---------------------------------------------------------------------------
__global__ __launch_bounds__(256) void s_kernel(
    const int* __restrict__ idx,
    const float* __restrict__ e1, const float* __restrict__ e2,
    const float* __restrict__ w,
    float* __restrict__ s1, float* __restrict__ s2)
{
    const int waveId = threadIdx.x >> 6;
    const int lane   = threadIdx.x & 63;
    const int node   = (blockIdx.x << 2) + waveId;   // 4 waves/block
    const int row    = idx[node];

    const float4* e1v = (const float4*)(e1 + (size_t)row * DIM);
    const float4* e2v = (const float4*)(e2 + (size_t)row * DIM);
    const float4* w1v = (const float4*)w;
    const float4* w2v = (const float4*)(w + DIM);

    float4 a  = e1v[lane];
    float4 b  = e2v[lane];
    float4 w1 = w1v[lane];
    float4 w2 = w2v[lane];

    float acc1 = tanhf(ALPHA * a.x) * w1.x + tanhf(ALPHA * a.y) * w1.y
               + tanhf(ALPHA * a.z) * w1.z + tanhf(ALPHA * a.w) * w1.w;
    float acc2 = tanhf(ALPHA * b.x) * w2.x + tanhf(ALPHA * b.y) * w2.y
               + tanhf(ALPHA * b.z) * w2.z + tanhf(ALPHA * b.w) * w2.w;

    #pragma unroll
    for (int off = 32; off > 0; off >>= 1) {
        acc1 += __shfl_down(acc1, off);
        acc2 += __shfl_down(acc2, off);
    }
    if (lane == 0) {
        s1[node] = acc1;
        s2[node] = acc2;
    }
}

// ---------------------------------------------------------------------------
// Kernel C: one block per output row.
//   scores[i,j] = leaky_relu(s1[i] + s2[j] + b)   (lr(x) = max(x, 0.2x))
//   m_i = lr(s1[i] + b + max_j s2[j])   (exact: lr strictly increasing)
//   out[i, idx[j]] = exp(scores - m_i) / sum_j exp(scores - m_i)
// 256 threads x 32 columns each; exp values held in registers between the
// denominator pass and the store pass (no recompute, no big LDS).
// ---------------------------------------------------------------------------
__global__ __launch_bounds__(256) void row_kernel(
    const float* __restrict__ s1, const float* __restrict__ s2,
    const int* __restrict__ idx, const float* __restrict__ att_b,
    float* __restrict__ out)
{
    __shared__ float lds[8];
    const int t    = threadIdx.x;
    const int lane = t & 63;
    const int wv   = t >> 6;
    const int row  = blockIdx.x;

    // Load this thread's 32 s2 values (8 x float4, coalesced, L2-resident)
    const float4* s2v = (const float4*)s2;
    float4 v[8];
    float lmax = -3.402823466e38f;
    #pragma unroll
    for (int k = 0; k < 8; ++k) {
        v[k] = s2v[k * 256 + t];
        lmax = fmaxf(lmax, fmaxf(fmaxf(v[k].x, v[k].y), fmaxf(v[k].z, v[k].w)));
    }

    // Block-wide max of s2 (butterfly within wave, then across 4 waves)
    #pragma unroll
    for (int off = 32; off > 0; off >>= 1)
        lmax = fmaxf(lmax, __shfl_xor(lmax, off));
    if (lane == 0) lds[wv] = lmax;
    __syncthreads();
    const float s2max = fmaxf(fmaxf(lds[0], lds[1]), fmaxf(lds[2], lds[3]));

    const float base = s1[row] + att_b[0];
    const float tm   = base + s2max;
    const float m    = fmaxf(tm, SLOPE * tm);    // exact row max of lr(scores)
    const float mexp = m * LOG2E;

    // exp pass: e = 2^(lr(base+s2)*log2e - m*log2e), accumulate denominator
    float e[32];
    float dsum = 0.0f;
    #pragma unroll
    for (int k = 0; k < 8; ++k) {
        float x0 = base + v[k].x, x1 = base + v[k].y;
        float x2 = base + v[k].z, x3 = base + v[k].w;
        x0 = fmaxf(x0, SLOPE * x0);
        x1 = fmaxf(x1, SLOPE * x1);
        x2 = fmaxf(x2, SLOPE * x2);
        x3 = fmaxf(x3, SLOPE * x3);
        e[4 * k + 0] = __builtin_amdgcn_exp2f(fmaf(x0, LOG2E, -mexp));
        e[4 * k + 1] = __builtin_amdgcn_exp2f(fmaf(x1, LOG2E, -mexp));
        e[4 * k + 2] = __builtin_amdgcn_exp2f(fmaf(x2, LOG2E, -mexp));
        e[4 * k + 3] = __builtin_amdgcn_exp2f(fmaf(x3, LOG2E, -mexp));
        dsum += (e[4 * k + 0] + e[4 * k + 1]) + (e[4 * k + 2] + e[4 * k + 3]);
    }

    // Block-wide sum for the softmax denominator
    #pragma unroll
    for (int off = 32; off > 0; off >>= 1)
        dsum += __shfl_xor(dsum, off);
    if (lane == 0) lds[4 + wv] = dsum;
    __syncthreads();
    const float denom = (lds[4] + lds[5]) + (lds[6] + lds[7]);
    const float inv = 1.0f / denom;

    // Store pass: out[row, idx[j]] = e/denom. Fast float4 path when the 4
    // indices are the contiguous aligned identity (true for idx = arange).
    const int4* idxv = (const int4*)idx;
    float* orow = out + (size_t)row * NNODES;
    #pragma unroll
    for (int k = 0; k < 8; ++k) {
        int4 iv = idxv[k * 256 + t];
        float4 r;
        r.x = e[4 * k + 0] * inv;
        r.y = e[4 * k + 1] * inv;
        r.z = e[4 * k + 2] * inv;
        r.w = e[4 * k + 3] * inv;
        const int c0 = (k * 256 + t) * 4;
        if (iv.x == c0 && iv.y == c0 + 1 && iv.z == c0 + 2 && iv.w == c0 + 3) {
            *(float4*)(orow + c0) = r;
        } else {
            orow[iv.x] = r.x;
            orow[iv.y] = r.y;
            orow[iv.z] = r.z;
            orow[iv.w] = r.w;
        }
    }
}

extern "C" void kernel_launch(void* const* d_in, const int* in_sizes, int n_in,
                              void* d_out, int out_size, void* d_ws, size_t ws_size,
                              hipStream_t stream) {
    const int*   idx   = (const int*)d_in[0];
    const float* emb1  = (const float*)d_in[1];
    const float* emb2  = (const float*)d_in[2];
    const float* att_w = (const float*)d_in[3];
    const float* att_b = (const float*)d_in[4];
    float* out = (float*)d_out;

    float* s1 = (float*)d_ws;          // 8192 floats
    float* s2 = s1 + NNODES;           // 8192 floats

    s_kernel<<<NNODES / 4, 256, 0, stream>>>(idx, emb1, emb2, att_w, s1, s2);
    row_kernel<<<NNODES, 256, 0, stream>>>(s1, s2, idx, att_b, out);
}

// Round 3
// 292.228 us; speedup vs baseline: 1.0081x; 1.0081x over previous
//
#include <hip/hip_runtime.h>
#include <math.h>

#define NNODES 8192
#define DIM 256
#define ALPHA 3.0f
#define SLOPE 0.2f
#define LOG2E 1.4426950408889634f

typedef float floatx4 __attribute__((ext_vector_type(4)));  // native vec for nt store

// ---------------------------------------------------------------------------
// Kernel A: per-node scores s1[n] = tanh(a*emb1[idx[n]]) . w[:256]
//                           s2[n] = tanh(a*emb2[idx[n]]) . w[256:]
// One wave (64 lanes) per node; each lane handles 4 contiguous floats.
// ---------------------------------------------------------------------------
__global__ __launch_bounds__(256) void s_kernel(
    const int* __restrict__ idx,
    const float* __restrict__ e1, const float* __restrict__ e2,
    const float* __restrict__ w,
    float* __restrict__ s1, float* __restrict__ s2)
{
    const int waveId = threadIdx.x >> 6;
    const int lane   = threadIdx.x & 63;
    const int node   = (blockIdx.x << 2) + waveId;   // 4 waves/block
    const int row    = idx[node];

    const float4* e1v = (const float4*)(e1 + (size_t)row * DIM);
    const float4* e2v = (const float4*)(e2 + (size_t)row * DIM);
    const float4* w1v = (const float4*)w;
    const float4* w2v = (const float4*)(w + DIM);

    float4 a  = e1v[lane];
    float4 b  = e2v[lane];
    float4 w1 = w1v[lane];
    float4 w2 = w2v[lane];

    float acc1 = tanhf(ALPHA * a.x) * w1.x + tanhf(ALPHA * a.y) * w1.y
               + tanhf(ALPHA * a.z) * w1.z + tanhf(ALPHA * a.w) * w1.w;
    float acc2 = tanhf(ALPHA * b.x) * w2.x + tanhf(ALPHA * b.y) * w2.y
               + tanhf(ALPHA * b.z) * w2.z + tanhf(ALPHA * b.w) * w2.w;

    #pragma unroll
    for (int off = 32; off > 0; off >>= 1) {
        acc1 += __shfl_down(acc1, off);
        acc2 += __shfl_down(acc2, off);
    }
    if (lane == 0) {
        s1[node] = acc1;
        s2[node] = acc2;
    }
}

// ---------------------------------------------------------------------------
// Kernel C: one block per output row.
//   scores[i,j] = leaky_relu(s1[i] + s2[j] + b)   (lr(x) = max(x, 0.2x))
//   m_i = lr(s1[i] + b + max_j s2[j])   (exact: lr strictly increasing)
//   out[i, idx[j]] = exp(scores - m_i) / sum_j exp(scores - m_i)
// 256 threads x 32 columns each; exp values held in registers between the
// denominator pass and the store pass. idx prefetched into registers so the
// store burst issues immediately after the denominator broadcast.
// Output stores are nontemporal (pure 256 MB stream, don't pollute L2).
// ---------------------------------------------------------------------------
__global__ __launch_bounds__(256) void row_kernel(
    const float* __restrict__ s1, const float* __restrict__ s2,
    const int* __restrict__ idx, const float* __restrict__ att_b,
    float* __restrict__ out)
{
    __shared__ float lds[8];
    const int t    = threadIdx.x;
    const int lane = t & 63;
    const int wv   = t >> 6;
    const int row  = blockIdx.x;

    // Prefetch idx (L2-resident) and s2 for this thread's 32 columns.
    const int4*   idxv = (const int4*)idx;
    const float4* s2v  = (const float4*)s2;
    int4   iv[8];
    float4 v[8];
    float lmax = -3.402823466e38f;
    #pragma unroll
    for (int k = 0; k < 8; ++k) {
        iv[k] = idxv[k * 256 + t];
        v[k]  = s2v[k * 256 + t];
        lmax = fmaxf(lmax, fmaxf(fmaxf(v[k].x, v[k].y), fmaxf(v[k].z, v[k].w)));
    }

    // Block-wide max of s2 (butterfly within wave, then across 4 waves)
    #pragma unroll
    for (int off = 32; off > 0; off >>= 1)
        lmax = fmaxf(lmax, __shfl_xor(lmax, off));
    if (lane == 0) lds[wv] = lmax;
    __syncthreads();
    const float s2max = fmaxf(fmaxf(lds[0], lds[1]), fmaxf(lds[2], lds[3]));

    const float base = s1[row] + att_b[0];
    const float tm   = base + s2max;
    const float m    = fmaxf(tm, SLOPE * tm);    // exact row max of lr(scores)
    const float mexp = m * LOG2E;

    // exp pass: e = 2^(lr(base+s2)*log2e - m*log2e), accumulate denominator
    float e[32];
    float dsum = 0.0f;
    #pragma unroll
    for (int k = 0; k < 8; ++k) {
        float x0 = base + v[k].x, x1 = base + v[k].y;
        float x2 = base + v[k].z, x3 = base + v[k].w;
        x0 = fmaxf(x0, SLOPE * x0);
        x1 = fmaxf(x1, SLOPE * x1);
        x2 = fmaxf(x2, SLOPE * x2);
        x3 = fmaxf(x3, SLOPE * x3);
        e[4 * k + 0] = __builtin_amdgcn_exp2f(fmaf(x0, LOG2E, -mexp));
        e[4 * k + 1] = __builtin_amdgcn_exp2f(fmaf(x1, LOG2E, -mexp));
        e[4 * k + 2] = __builtin_amdgcn_exp2f(fmaf(x2, LOG2E, -mexp));
        e[4 * k + 3] = __builtin_amdgcn_exp2f(fmaf(x3, LOG2E, -mexp));
        dsum += (e[4 * k + 0] + e[4 * k + 1]) + (e[4 * k + 2] + e[4 * k + 3]);
    }

    // Block-wide sum for the softmax denominator
    #pragma unroll
    for (int off = 32; off > 0; off >>= 1)
        dsum += __shfl_xor(dsum, off);
    if (lane == 0) lds[4 + wv] = dsum;
    __syncthreads();
    const float denom = (lds[4] + lds[5]) + (lds[6] + lds[7]);
    const float inv = 1.0f / denom;

    // Store pass: out[row, idx[j]] = e/denom. Fast nontemporal float4 path
    // when the 4 indices are the contiguous aligned identity (idx = arange).
    float* orow = out + (size_t)row * NNODES;
    #pragma unroll
    for (int k = 0; k < 8; ++k) {
        floatx4 r;
        r.x = e[4 * k + 0] * inv;
        r.y = e[4 * k + 1] * inv;
        r.z = e[4 * k + 2] * inv;
        r.w = e[4 * k + 3] * inv;
        const int c0 = (k * 256 + t) * 4;
        if (iv[k].x == c0 && iv[k].y == c0 + 1 && iv[k].z == c0 + 2 && iv[k].w == c0 + 3) {
            __builtin_nontemporal_store(r, (floatx4*)(orow + c0));
        } else {
            orow[iv[k].x] = r.x;
            orow[iv[k].y] = r.y;
            orow[iv[k].z] = r.z;
            orow[iv[k].w] = r.w;
        }
    }
}

extern "C" void kernel_launch(void* const* d_in, const int* in_sizes, int n_in,
                              void* d_out, int out_size, void* d_ws, size_t ws_size,
                              hipStream_t stream) {
    const int*   idx   = (const int*)d_in[0];
    const float* emb1  = (const float*)d_in[1];
    const float* emb2  = (const float*)d_in[2];
    const float* att_w = (const float*)d_in[3];
    const float* att_b = (const float*)d_in[4];
    float* out = (float*)d_out;

    float* s1 = (float*)d_ws;          // 8192 floats
    float* s2 = s1 + NNODES;           // 8192 floats

    s_kernel<<<NNODES / 4, 256, 0, stream>>>(idx, emb1, emb2, att_w, s1, s2);
    row_kernel<<<NNODES, 256, 0, stream>>>(s1, s2, idx, att_b, out);
}